// Round 16
// baseline (137.365 us; speedup 1.0000x reference)
//
#include <hip/hip_runtime.h>
#include <hip/hip_fp8.h>

// NCE loss: out0 = align + w*uniform, out1 = align, out2 = uniform
// align[n]   = logsig(ref[n]·pos[n]/T)
// uniform[n] = mean_m logsig(-ref[n]·neg[m]/T)
// N=M=8192, D=512, T=0.5, w=1.0
//
// Round 16: LDS-FREE streaming GEMM. MX-fp8 (e4m3, scale=1.0) 16x16x128;
// MFMA fragments loaded directly from global (L2-resident: A-band 128KB +
// B 4MB per XCD) into registers. No LDS, no swizzle, no barriers -> L2
// delivery, MFMA, and epilogue VALU overlap freely across 12-16 waves/CU
// instead of serializing at per-K-tile barriers (r15 post-mortem: measured
// 70us ~= sum of pipes). align-dot fused into cvt_pack; tiny combine.

typedef __attribute__((ext_vector_type(4)))  float f32x4;
typedef __attribute__((ext_vector_type(4)))  int   int4v;
typedef __attribute__((ext_vector_type(8)))  int   int8v;
typedef __attribute__((ext_vector_type(16))) unsigned char uchar16;

constexpr int N_ = 8192;
constexpr int M_ = 8192;
constexpr int D_ = 512;
constexpr float INV_T = 2.0f;
constexpr float NEG_W = 1.0f;
constexpr float LOG2E = 1.4426950408889634f;
constexpr float LN2   = 0.6931471805599453f;
constexpr unsigned SCALE1 = 0x7F7F7F7Fu;  // E8M0 127 -> 2^0 = 1.0

__device__ __forceinline__ float logsig_neg(float s) {
  float t = __builtin_fabsf(s);
  float e = __builtin_amdgcn_exp2f(-t * LOG2E);
  float l = __builtin_amdgcn_logf(1.0f + e) * LN2;
  return fminf(-s, 0.0f) - l;
}

// fp32 -> fp8 e4m3, PLAIN row-major (no swizzle: gemm has no LDS).
// Also computes align-dot (ref.pos) for ref rows (block owns 8 full rows).
__global__ __launch_bounds__(256) void cvt_pack(
    const float* __restrict__ refp, const float* __restrict__ posp,
    const float* __restrict__ negp, unsigned char* __restrict__ a8,
    unsigned char* __restrict__ b8, float* __restrict__ aligndot) {
  const int b = blockIdx.x;
  const bool isA = (b < 1024);
  const float* src = isA ? refp : negp;
  unsigned char* dst = isA ? a8 : b8;
  const int t   = threadIdx.x;
  const int row = (b & 1023) * 8 + (t >> 5);
  const int ck  = t & 31;  // 16B chunk within row
  const float* sp = src + (size_t)row * 512 + ck * 16;
  f32x4 v[4];
#pragma unroll
  for (int q = 0; q < 4; ++q) v[q] = reinterpret_cast<const f32x4*>(sp)[q];
  uchar16 o;
#pragma unroll
  for (int q = 0; q < 4; ++q)
#pragma unroll
    for (int j = 0; j < 4; ++j) {
      __hip_fp8_e4m3 f(v[q][j]);
      o[q * 4 + j] = f.__x;
    }
  if (isA) {
    const float* pp = posp + (size_t)row * 512 + ck * 16;
    float dot = 0.0f;
#pragma unroll
    for (int q = 0; q < 4; ++q) {
      f32x4 pv = reinterpret_cast<const f32x4*>(pp)[q];
#pragma unroll
      for (int j = 0; j < 4; ++j) dot = __builtin_fmaf(v[q][j], pv[j], dot);
    }
    dot += __shfl_xor(dot, 1);
    dot += __shfl_xor(dot, 2);
    dot += __shfl_xor(dot, 4);
    dot += __shfl_xor(dot, 8);
    dot += __shfl_xor(dot, 16);
    if (ck == 0) aligndot[row] = dot;
  }
  *reinterpret_cast<uchar16*>(dst + (size_t)row * 512 + ck * 16) = o;
}

__global__ __launch_bounds__(256) void nce_gemm(
    const unsigned char* __restrict__ A,  // ref fp8, row-major
    const unsigned char* __restrict__ B,  // neg fp8, row-major
    float* __restrict__ rowsum) {         // (N,) fp32, pre-zeroed
  const int tid  = threadIdx.x;
  const int lane = tid & 63;
  const int wid  = tid >> 6;   // 0..3
  const int wr   = wid >> 1;   // 0..1 (A half: 64 rows)
  const int wc   = wid & 1;    // 0..1 (B half: 64 cols)

  // XCD swizzle: 4096 blocks, 8 XCDs, 8-row bands, column-major in band
  // (per XCD: A band 1024 rows = 512KB fp8 + streams B -> L2-resident)
  const int bid  = blockIdx.x;
  const int x    = bid & 7;
  const int t    = bid >> 3;   // 0..511
  const int brow = (x * 8 + (t & 7)) * 128;
  const int bcol = (t >> 3) * 128;

  // fragment lane mapping (16x16x128): lane holds row (lane&15),
  // K-bytes [(lane>>4)*32, +32) of the K-tile.
  const int r  = lane & 15;
  const int g4 = lane >> 4;

  // per-lane base pointers (row-major, no swizzle)
  const char* pA = reinterpret_cast<const char*>(A) +
                   (size_t)(brow + wr * 64 + r) * 512 + g4 * 32;
  const char* pB = reinterpret_cast<const char*>(B) +
                   (size_t)(bcol + wc * 64 + r) * 512 + g4 * 32;

  f32x4 acc[4][4] = {};

  // ---- main loop: 4 K-tiles of 128, fully unrolled, no barriers ----
#pragma unroll
  for (int kt = 0; kt < 4; ++kt) {
    int8v aF[4], bF[4];
#pragma unroll
    for (int mf = 0; mf < 4; ++mf) {
      const char* p = pA + (size_t)(mf * 16) * 512 + kt * 128;
      int4v lo = *reinterpret_cast<const int4v*>(p);
      int4v hi = *reinterpret_cast<const int4v*>(p + 16);
      aF[mf] = __builtin_shufflevector(lo, hi, 0, 1, 2, 3, 4, 5, 6, 7);
    }
#pragma unroll
    for (int nf = 0; nf < 4; ++nf) {
      const char* p = pB + (size_t)(nf * 16) * 512 + kt * 128;
      int4v lo = *reinterpret_cast<const int4v*>(p);
      int4v hi = *reinterpret_cast<const int4v*>(p + 16);
      bF[nf] = __builtin_shufflevector(lo, hi, 0, 1, 2, 3, 4, 5, 6, 7);
    }
#pragma unroll
    for (int mf = 0; mf < 4; ++mf)
#pragma unroll
      for (int nf = 0; nf < 4; ++nf)
        acc[mf][nf] = __builtin_amdgcn_mfma_scale_f32_16x16x128_f8f6f4(
            aF[mf], bF[nf], acc[mf][nf], 0, 0, 0, SCALE1, 0, SCALE1);
  }

  // ---- epilogue: uni = logsig(-s*INV_T); reduce this wave's 64 cols ----
  float part[16];
#pragma unroll
  for (int mf = 0; mf < 4; ++mf)
#pragma unroll
    for (int rr = 0; rr < 4; ++rr) {
      float ssum = 0.0f;
#pragma unroll
      for (int nf = 0; nf < 4; ++nf) {
        float s = acc[mf][nf][rr] * INV_T;
        ssum += logsig_neg(s);
      }
      part[mf * 4 + rr] = ssum;
    }
#pragma unroll
  for (int i = 0; i < 16; ++i) {
    float v = part[i];
    v += __shfl_xor(v, 1);
    v += __shfl_xor(v, 2);
    v += __shfl_xor(v, 4);
    v += __shfl_xor(v, 8);
    part[i] = v;
  }
  if ((lane & 15) == 0) {
#pragma unroll
    for (int mf = 0; mf < 4; ++mf)
#pragma unroll
      for (int rr = 0; rr < 4; ++rr)
        atomicAdd(&rowsum[brow + wr * 64 + mf * 16 + g4 * 4 + rr],
                  part[mf * 4 + rr]);
  }
}

__global__ __launch_bounds__(256) void nce_combine(
    const float* __restrict__ aligndot, const float* __restrict__ rowsum,
    float* __restrict__ out) {
  const int n = blockIdx.x * 256 + threadIdx.x;
  float z = aligndot[n] * INV_T;
  float align   = logsig_neg(-z);
  float uniform = rowsum[n] * (1.0f / (float)M_);
  out[n]          = align + NEG_W * uniform;
  out[N_ + n]     = align;
  out[2 * N_ + n] = uniform;
}

extern "C" void kernel_launch(void* const* d_in, const int* in_sizes, int n_in,
                              void* d_out, int out_size, void* d_ws,
                              size_t ws_size, hipStream_t stream) {
  const float* ref = (const float*)d_in[0];
  const float* pos = (const float*)d_in[1];
  const float* neg = (const float*)d_in[2];
  float* out = (float*)d_out;

  float* rowsum   = (float*)d_ws;                    // 32 KB
  float* aligndot = (float*)((char*)d_ws + 32768);   // 32 KB
  unsigned char* a8 = (unsigned char*)d_ws + 65536;  // 4 MB
  unsigned char* b8 = a8 + (size_t)N_ * D_;          // 4 MB

  hipMemsetAsync(rowsum, 0, N_ * sizeof(float), stream);
  cvt_pack<<<2048, 256, 0, stream>>>(ref, pos, neg, a8, b8, aligndot);
  nce_gemm<<<4096, 256, 0, stream>>>(a8, b8, rowsum);
  nce_combine<<<N_ / 256, 256, 0, stream>>>(aligndot, rowsum, out);
}